// Round 8
// baseline (202.702 us; speedup 1.0000x reference)
//
#include <hip/hip_runtime.h>
#include <hip/hip_bf16.h>

// Problem constants
#define B_    2
#define S_    2048
#define DIM_  512
#define H_    8
#define HD_   64
#define TOUT_ 1536   // 2*QK + DIM
#define ROWS_ (B_ * S_)   // 4096

typedef unsigned short ushort_t;
typedef __attribute__((ext_vector_type(8))) __bf16 bf16x8;
typedef __attribute__((ext_vector_type(4))) float floatx4;
typedef __attribute__((ext_vector_type(16))) float floatx16;

#define AS_GLB __attribute__((address_space(1)))
#define AS_LDS __attribute__((address_space(3)))

// ---------- numeric helpers ----------
__device__ __forceinline__ float bf2f(unsigned int u) { return __uint_as_float(u << 16); }
__device__ __forceinline__ unsigned int f2bfu(float f) {
    unsigned u = __float_as_uint(f);
    return (u + 0x7fffu + ((u >> 16) & 1u)) >> 16;
}
__device__ __forceinline__ bf16x8 cvt8(const float* p) {
    float4 a = *reinterpret_cast<const float4*>(p);
    float4 b = *reinterpret_cast<const float4*>(p + 4);
    ushort_t o[8] = {(ushort_t)f2bfu(a.x), (ushort_t)f2bfu(a.y), (ushort_t)f2bfu(a.z), (ushort_t)f2bfu(a.w),
                     (ushort_t)f2bfu(b.x), (ushort_t)f2bfu(b.y), (ushort_t)f2bfu(b.z), (ushort_t)f2bfu(b.w)};
    return *reinterpret_cast<bf16x8*>(o);
}

// ---------- mask classification (proven R1-R7) ----------
__global__ void tmha_detect(const unsigned char* mb, int* flags) {
    __shared__ int s_bf, s_f, s_u8;
    int tid = threadIdx.x;
    if (tid == 0) { s_bf = 0; s_f = 0; s_u8 = 0; }
    __syncthreads();
    int cbf = 0, cf = 0, cu8 = 0;
    for (int i = tid; i < 4096; i += 256) {
        unsigned char v = mb[i];
        if (v == 0x3F || v == 0x80) {
            cf++;
            if ((i & 3) == 1) cbf++;
        } else if (v != 0 && (i & 3) != 0) {
            cu8++;
        }
    }
    atomicAdd(&s_bf, cbf); atomicAdd(&s_f, cf); atomicAdd(&s_u8, cu8);
    __syncthreads();
    if (tid == 0) {
        int mcls;
        if (s_bf > 0)      mcls = 2;
        else if (s_f > 0)  mcls = 3;
        else if (s_u8 > 0) mcls = 0;
        else               mcls = 1;
        flags[1] = mcls;
    }
}

__global__ void tmha_decode_mask(const unsigned char* mb, const int* flags, int* wm) {
    int i = blockIdx.x * 256 + threadIdx.x;
    if (i >= ROWS_) return;
    int cls = flags[1];
    int v;
    if (cls == 0)      v = (mb[i] != 0);
    else if (cls == 1) v = (reinterpret_cast<const int*>(mb)[i] != 0);
    else if (cls == 2) v = ((reinterpret_cast<const unsigned short*>(mb)[i] & 0x7fffu) != 0);
    else               v = ((reinterpret_cast<const unsigned int*>(mb)[i] & 0x7fffffffu) != 0);
    wm[i] = v;
}

// ---------- fp32 -> bf16 cast (vectorized) ----------
__global__ __launch_bounds__(256) void cast_bf16(const float* __restrict__ src,
                                                 ushort_t* __restrict__ dst, int n4) {
    int i = blockIdx.x * 256 + threadIdx.x;
    if (i >= n4) return;
    float4 v = reinterpret_cast<const float4*>(src)[i];
    ushort_t o[4] = {(ushort_t)f2bfu(v.x), (ushort_t)f2bfu(v.y), (ushort_t)f2bfu(v.z), (ushort_t)f2bfu(v.w)};
    reinterpret_cast<uint2*>(dst)[i] = *reinterpret_cast<uint2*>(o);
}

// ==================================================================
// MFMA GEMM (proven R5): C[M,N] = A[M,K] @ B[N,K]^T, XOR-swizzled LDS.
// ==================================================================
template <int TM, int N, int K>
__global__ __launch_bounds__(256) void mfma_gemm_bt(const ushort_t* __restrict__ A,
                                                    const ushort_t* __restrict__ Bm,
                                                    float* __restrict__ C) {
    constexpr int FM = TM / 32;
    __shared__ __align__(16) ushort_t As[TM * 64];
    __shared__ __align__(16) ushort_t Bs[128 * 64];
    int tid = threadIdx.x;
    int lane = tid & 63;
    int wv = tid >> 6;
    int wm = wv >> 1, wn = wv & 1;
    int quad = lane >> 4;
    int mrow = lane & 15;
    int bx = blockIdx.x;
    int by = blockIdx.y;

    floatx4 acc[FM][4];
#pragma unroll
    for (int i = 0; i < FM; i++)
#pragma unroll
        for (int j = 0; j < 4; j++) acc[i][j] = (floatx4){0.f, 0.f, 0.f, 0.f};

    for (int k0 = 0; k0 < K; k0 += 64) {
#pragma unroll
        for (int t = 0; t < TM / 32; t++) {
            int p = (wv * (TM / 32) + t) * 64 + lane;
            int row = p >> 3, cp = p & 7;
            int gc = cp ^ (row & 7);
            const ushort_t* ga = A + (size_t)(by * TM + row) * K + k0 + gc * 8;
            __builtin_amdgcn_global_load_lds((const AS_GLB unsigned int*)ga,
                                             (AS_LDS unsigned int*)&As[(size_t)(wv * (TM / 32) + t) * 64 * 8],
                                             16, 0, 0);
        }
#pragma unroll
        for (int t = 0; t < 4; t++) {
            int p = (wv * 4 + t) * 64 + lane;
            int row = p >> 3, cp = p & 7;
            int gc = cp ^ (row & 7);
            const ushort_t* gb = Bm + (size_t)(bx * 128 + row) * K + k0 + gc * 8;
            __builtin_amdgcn_global_load_lds((const AS_GLB unsigned int*)gb,
                                             (AS_LDS unsigned int*)&Bs[(size_t)(wv * 4 + t) * 64 * 8],
                                             16, 0, 0);
        }
        __syncthreads();
#pragma unroll
        for (int ks = 0; ks < 64; ks += 32) {
            int c = (ks >> 3) + quad;
            bf16x8 af[FM], bf[4];
#pragma unroll
            for (int i = 0; i < FM; i++) {
                int row = wm * (TM / 2) + i * 16 + mrow;
                int pos = row * 8 + (c ^ (row & 7));
                af[i] = *reinterpret_cast<const bf16x8*>(&As[pos * 8]);
            }
#pragma unroll
            for (int j = 0; j < 4; j++) {
                int row = wn * 64 + j * 16 + mrow;
                int pos = row * 8 + (c ^ (row & 7));
                bf[j] = *reinterpret_cast<const bf16x8*>(&Bs[pos * 8]);
            }
#pragma unroll
            for (int i = 0; i < FM; i++)
#pragma unroll
                for (int j = 0; j < 4; j++)
                    acc[i][j] = __builtin_amdgcn_mfma_f32_16x16x32_bf16(af[i], bf[j], acc[i][j], 0, 0, 0);
        }
        __syncthreads();
    }

    int col0 = bx * 128 + wn * 64 + mrow;
    int row0 = by * TM + wm * (TM / 2) + quad * 4;
#pragma unroll
    for (int i = 0; i < FM; i++)
#pragma unroll
        for (int j = 0; j < 4; j++)
#pragma unroll
            for (int r = 0; r < 4; r++)
                C[(size_t)(row0 + i * 16 + r) * N + col0 + j * 16] = acc[i][j][r];
}

// ==================================================================
// MFMA rotation (proven R6): per position s, out = in @ R_s^T if mask.
// ==================================================================
__global__ __launch_bounds__(256) void rot_qk_mfma(const float* __restrict__ t,
                                                   const float* __restrict__ rotG,
                                                   const int* __restrict__ wm,
                                                   ushort_t* __restrict__ Qb,
                                                   ushort_t* __restrict__ Kb) {
    int lane = threadIdx.x & 63;
    int wv = threadIdx.x >> 6;
    int row = blockIdx.x * 4 + wv;     // b*2048 + s
    int b = row >> 11, s = row & 2047;
    int lm = lane & 15, quad = lane >> 4;
    const float* trow = t + (size_t)row * TOUT_;

    if (wm[row]) {
        bf16x8 af[2];
#pragma unroll
        for (int kc = 0; kc < 2; kc++)
            af[kc] = cvt8(trow + lm * 64 + kc * 32 + quad * 8);

        const float* R = rotG + (size_t)row * 4096;
        floatx4 dacc[4];
#pragma unroll
        for (int nb = 0; nb < 4; nb++) dacc[nb] = (floatx4){0.f, 0.f, 0.f, 0.f};
#pragma unroll
        for (int nb = 0; nb < 4; nb++)
#pragma unroll
            for (int kc = 0; kc < 2; kc++) {
                bf16x8 bfr = cvt8(R + (size_t)(nb * 16 + lm) * 64 + kc * 32 + quad * 8);
                dacc[nb] = __builtin_amdgcn_mfma_f32_16x16x32_bf16(af[kc], bfr, dacc[nb], 0, 0, 0);
            }
#pragma unroll
        for (int nb = 0; nb < 4; nb++)
#pragma unroll
            for (int r = 0; r < 4; r++) {
                int vec = quad * 4 + r;
                int h = vec & 7;
                ushort_t* dst = (vec >= 8 ? Kb : Qb);
                dst[((size_t)(b * 8 + h) * 2048 + s) * 64 + nb * 16 + lm] = (ushort_t)f2bfu(dacc[nb][r]);
            }
    } else {
#pragma unroll
        for (int nb = 0; nb < 4; nb++)
#pragma unroll
            for (int r = 0; r < 4; r++) {
                int vec = quad * 4 + r;
                int h = vec & 7;
                float v = trow[vec * 64 + nb * 16 + lm];
                ushort_t* dst = (vec >= 8 ? Kb : Qb);
                dst[((size_t)(b * 8 + h) * 2048 + s) * 64 + nb * 16 + lm] = (ushort_t)f2bfu(v);
            }
    }
}

// ---------- prep: V^T bf16 [bh][65][2048]; masked keys zeroed; row 64 = mask (proven R4) ----------
__global__ __launch_bounds__(256) void prep_vt(const float* __restrict__ t,
                                               const int* __restrict__ wm,
                                               ushort_t* __restrict__ VtG) {
    __shared__ float tile[64][65];
    __shared__ float mrow[64];
    int st = blockIdx.x;   // 0..31 (64-key tile)
    int bh = blockIdx.y;   // 0..15
    int b = bh >> 3, h = bh & 7;
    int tid = threadIdx.x;
    if (tid < 64) mrow[tid] = wm[b * 2048 + st * 64 + tid] ? 1.0f : 0.0f;
#pragma unroll
    for (int i = 0; i < 4; i++) {
        int q = i * 256 + tid;
        int r = q >> 4, c4 = (q & 15) * 4;
        float4 v = *reinterpret_cast<const float4*>(
            t + (size_t)(b * 2048 + st * 64 + r) * TOUT_ + 1024 + h * 64 + c4);
        tile[r][c4] = v.x; tile[r][c4 + 1] = v.y; tile[r][c4 + 2] = v.z; tile[r][c4 + 3] = v.w;
    }
    __syncthreads();
#pragma unroll
    for (int i = 0; i < 8; i++) {
        int e = i * 256 + tid;
        int d = e >> 5, sl = (e & 31) * 2;
        float v0 = tile[sl][d] * mrow[sl];
        float v1 = tile[sl + 1][d] * mrow[sl + 1];
        unsigned int u = f2bfu(v0) | (f2bfu(v1) << 16);
        *reinterpret_cast<unsigned int*>(VtG + ((size_t)bh * 65 + d) * 2048 + st * 64 + sl) = u;
    }
    if (tid < 32) {
        int sl = tid * 2;
        unsigned m0 = mrow[sl]     != 0.f ? 0x3F80u : 0u;
        unsigned m1 = mrow[sl + 1] != 0.f ? 0x3F80u : 0u;
        *reinterpret_cast<unsigned int*>(VtG + ((size_t)bh * 65 + 64) * 2048 + st * 64 + sl) = m0 | (m1 << 16);
    }
}

// ==================================================================
// MFMA flash taylor-attention, v4: 32x32x16 MFMAs (2x FLOP per LDS
// fragment read). Block = 64q, 4 waves = (qg,kg) 2x2; wave = 32q x 64keys.
// S^T = K·Q^T so P stores pack to ds_write_b64; P layout [q][key]
// (16B-granule XOR swizzle) doubles as the PV A-operand layout.
// Denominator via mask ones-row (Ms) + 16B zero broadcast (Zb) for pad.
// Split-K: outer ks (2) x inner kg (2) -> 4 fp32 numer/den slots.
// LDS 49.4 KB -> 3 blocks/CU (12 waves).
// ==================================================================
__global__ __launch_bounds__(256, 3) void tmha_attn_mfma(const ushort_t* __restrict__ Qb,
                                                         const ushort_t* __restrict__ Kb,
                                                         const ushort_t* __restrict__ VtG,
                                                         float* __restrict__ numer,
                                                         float* __restrict__ den) {
    __shared__ __align__(16) ushort_t Ks[128 * 64];   // [key][8 gran]  16 KB
    __shared__ __align__(16) ushort_t Vs[64 * 128];   // [dim][16 gran] 16 KB
    __shared__ __align__(16) ushort_t Ps[64 * 128];   // [q][16 gran]   16 KB
    __shared__ __align__(16) ushort_t Ms[128];        // mask row bf16
    __shared__ __align__(16) ushort_t Zb[8];          // 16B zero broadcast
    int tid = threadIdx.x;
    int lane = tid & 63;
    int wv = tid >> 6;
    int qg = wv >> 1, kg = wv & 1;
    int l31 = lane & 31, lhi = lane >> 5;
    int qt = blockIdx.x;
    int h = blockIdx.y;
    int z = blockIdx.z;
    int b = z >> 1, ks = z & 1;
    int bh = b * 8 + h;
    if (tid < 4) reinterpret_cast<unsigned int*>(Zb)[tid] = 0u;

    // Q as B-operand fragments: lane n=q(l31), k = kstep*16 + lhi*8 + i
    bf16x8 qf[4];
    {
        const ushort_t* qp = Qb + ((size_t)bh * 2048 + qt * 64 + qg * 32 + l31) * 64 + lhi * 8;
        qf[0] = *reinterpret_cast<const bf16x8*>(qp);
        qf[1] = *reinterpret_cast<const bf16x8*>(qp + 16);
        qf[2] = *reinterpret_cast<const bf16x8*>(qp + 32);
        qf[3] = *reinterpret_cast<const bf16x8*>(qp + 48);
    }

    floatx16 oacc[3];
#pragma unroll
    for (int nt = 0; nt < 3; nt++)
#pragma unroll
        for (int e = 0; e < 16; e++) oacc[nt][e] = 0.f;

    int q = qg * 32 + l31;

    for (int kt = ks * 1024; kt < ks * 1024 + 1024; kt += 128) {
        // ---- stage K: 128 keys x 8 granules, swizzle g^(row&7) ----
#pragma unroll
        for (int t4 = 0; t4 < 4; t4++) {
            int p = (wv * 4 + t4) * 64 + lane;
            int row = p >> 3, cp = p & 7;
            int gc = cp ^ (row & 7);
            const ushort_t* g = Kb + ((size_t)bh * 2048 + kt + row) * 64 + gc * 8;
            __builtin_amdgcn_global_load_lds((const AS_GLB unsigned int*)g,
                                             (AS_LDS unsigned int*)&Ks[(size_t)(wv * 4 + t4) * 64 * 8],
                                             16, 0, 0);
        }
        // ---- stage V dims 0..63: 64 rows x 16 granules, swizzle g^(row&15) ----
#pragma unroll
        for (int t4 = 0; t4 < 4; t4++) {
            int p = (wv * 4 + t4) * 64 + lane;
            int row = p >> 4, cp = p & 15;
            int gc = cp ^ (row & 15);
            const ushort_t* g = VtG + ((size_t)bh * 65 + row) * 2048 + kt + gc * 8;
            __builtin_amdgcn_global_load_lds((const AS_GLB unsigned int*)g,
                                             (AS_LDS unsigned int*)&Vs[(size_t)(wv * 4 + t4) * 64 * 8],
                                             16, 0, 0);
        }
        // ---- mask row (128 keys bf16) ----
        if (tid < 64) {
            reinterpret_cast<unsigned int*>(Ms)[tid] = *reinterpret_cast<const unsigned int*>(
                VtG + ((size_t)bh * 65 + 64) * 2048 + kt + tid * 2);
        }
        __syncthreads();

        // ---- S^T = K · Q^T : wave computes keys kg*64..+64 x 32 q ----
        floatx16 sacc[2];
#pragma unroll
        for (int mt = 0; mt < 2; mt++)
#pragma unroll
            for (int e = 0; e < 16; e++) sacc[mt][e] = 0.f;
#pragma unroll
        for (int kstep = 0; kstep < 4; kstep++) {
            int g = kstep * 2 + lhi;
#pragma unroll
            for (int mt = 0; mt < 2; mt++) {
                int row = kg * 64 + mt * 32 + l31;
                int pos = row * 8 + (g ^ (row & 7));
                bf16x8 kf = *reinterpret_cast<const bf16x8*>(&Ks[pos * 8]);
                sacc[mt] = __builtin_amdgcn_mfma_f32_32x32x16_bf16(kf, qf[kstep], sacc[mt], 0, 0, 0);
            }
        }

        // ---- taylor weights -> Ps (packed b64): C row=key, col=q ----
#pragma unroll
        for (int mt = 0; mt < 2; mt++)
#pragma unroll
            for (int gg = 0; gg < 4; gg++) {
                float w[4];
#pragma unroll
                for (int r = 0; r < 4; r++) {
                    float s = sacc[mt][gg * 4 + r];
                    w[r] = fmaf(s, fmaf(s, 0.0078125f, 0.125f), 1.0f);  // 1 + s/8 + s^2/128
                }
                int k0 = kg * 64 + mt * 32 + gg * 8 + lhi * 4;   // 4 consecutive keys
                int g16 = k0 >> 3;
                int pos = q * 16 + (g16 ^ (q & 15));
                uint2 u;
                u.x = f2bfu(w[0]) | (f2bfu(w[1]) << 16);
                u.y = f2bfu(w[2]) | (f2bfu(w[3]) << 16);
                *reinterpret_cast<uint2*>(&Ps[pos * 8 + (k0 & 7)]) = u;
            }
        __syncthreads();

        // ---- O += P · V' : wave uses its kg key-half; n-tiles {0-31,32-63,64-95} ----
#pragma unroll
        for (int kstep = 0; kstep < 4; kstep++) {
            int gk = kg * 8 + kstep * 2 + lhi;
            int ppos = q * 16 + (gk ^ (q & 15));
            bf16x8 pa = *reinterpret_cast<const bf16x8*>(&Ps[ppos * 8]);
#pragma unroll
            for (int nt = 0; nt < 3; nt++) {
                int vrow = nt * 32 + l31;
                const ushort_t* vp;
                if (vrow < 64)       vp = &Vs[(vrow * 16 + (gk ^ (vrow & 15))) * 8];
                else if (vrow == 64) vp = &Ms[gk * 8];
                else                 vp = Zb;
                bf16x8 vb = *reinterpret_cast<const bf16x8*>(vp);
                oacc[nt] = __builtin_amdgcn_mfma_f32_32x32x16_bf16(pa, vb, oacc[nt], 0, 0, 0);
            }
        }
        __syncthreads();
    }

    // ---- epilogue: write slot numer (fp32) + den ----
    int sidx = ks * 2 + kg;
    int qbase = b * 2048 + qt * 64 + qg * 32;
#pragma unroll
    for (int nt = 0; nt < 2; nt++)
#pragma unroll
        for (int gg = 0; gg < 4; gg++)
#pragma unroll
            for (int r = 0; r < 4; r++) {
                int qrow = qbase + r + 8 * gg + 4 * lhi;
                numer[((size_t)sidx * ROWS_ + qrow) * DIM_ + h * 64 + nt * 32 + l31] = oacc[nt][gg * 4 + r];
            }
    if (l31 == 0) {
#pragma unroll
        for (int gg = 0; gg < 4; gg++)
#pragma unroll
            for (int r = 0; r < 4; r++) {
                int qrow = qbase + r + 8 * gg + 4 * lhi;
                den[((size_t)sidx * ROWS_ + qrow) * 8 + h] = oacc[2][gg * 4 + r];
            }
    }
}

// ---------- combine 4 splits: attn = Σn / Σd, bf16 ----------
__global__ __launch_bounds__(256) void attn_combine(const float* __restrict__ numer,
                                                    const float* __restrict__ den,
                                                    ushort_t* __restrict__ attnAb) {
    int i = blockIdx.x * 256 + threadIdx.x;      // over 4096*128 float4s
    int row = i >> 7;
    int c4 = (i & 127) * 4;
    int h = c4 >> 6;
    float nx = 0.f, ny = 0.f, nz = 0.f, nw = 0.f, d = 0.f;
#pragma unroll
    for (int s = 0; s < 4; s++) {
        float4 n = *reinterpret_cast<const float4*>(&numer[((size_t)s * ROWS_ + row) * DIM_ + c4]);
        nx += n.x; ny += n.y; nz += n.z; nw += n.w;
        d += den[((size_t)s * ROWS_ + row) * 8 + h];
    }
    float inv = 1.0f / d;
    ushort_t o[4] = {(ushort_t)f2bfu(nx * inv), (ushort_t)f2bfu(ny * inv),
                     (ushort_t)f2bfu(nz * inv), (ushort_t)f2bfu(nw * inv)};
    *reinterpret_cast<uint2*>(&attnAb[(size_t)row * DIM_ + c4]) = *reinterpret_cast<uint2*>(o);
}

extern "C" void kernel_launch(void* const* d_in, const int* in_sizes, int n_in,
                              void* d_out, int out_size, void* d_ws, size_t ws_size,
                              hipStream_t stream) {
    (void)in_sizes; (void)n_in; (void)out_size; (void)ws_size;
    const float* x    = (const float*)d_in[0];
    const void*  mask = d_in[1];
    const float* rot  = (const float*)d_in[2];
    const float* Wt   = (const float*)d_in[3];
    const float* Wo   = (const float*)d_in[4];

    char* ws = (char*)d_ws;
    int* flags       = (int*)ws;                            // 64 B
    int* wmask       = (int*)(ws + 64);                     // 16 KB
    float* t         = (float*)(ws + 32768);                // 25,165,824 B
    ushort_t* Xb     = (ushort_t*)(ws + 25198592);          //  4,194,304 B
    ushort_t* Wtb    = (ushort_t*)(ws + 29392896);          //  1,572,864 B
    ushort_t* Wob    = (ushort_t*)(ws + 30965760);          //    524,288 B
    ushort_t* Qb     = (ushort_t*)(ws + 31490048);          //  4,194,304 B
    ushort_t* Kb     = (ushort_t*)(ws + 35684352);          //  4,194,304 B
    ushort_t* VtG    = (ushort_t*)(ws + 39878656);          //  4,259,840 B
    ushort_t* attnAb = (ushort_t*)(ws + 44138496);          //  4,194,304 B -> ends 48,332,800
    float* numer     = (float*)(ws + 50331648);             // 4 * 4096 * 512 * 4 = 33,554,432 B
    float* den       = (float*)(ws + 83886080);             // 4 * 4096 * 8 * 4 = 524,288 B

    tmha_detect<<<1, 256, 0, stream>>>((const unsigned char*)mask, flags);
    tmha_decode_mask<<<16, 256, 0, stream>>>((const unsigned char*)mask, flags, wmask);

    // bf16 casts
    cast_bf16<<<(ROWS_ * DIM_ / 4 + 255) / 256, 256, 0, stream>>>(x, Xb, ROWS_ * DIM_ / 4);
    cast_bf16<<<(TOUT_ * DIM_ / 4 + 255) / 256, 256, 0, stream>>>(Wt, Wtb, TOUT_ * DIM_ / 4);
    cast_bf16<<<(DIM_ * DIM_ / 4 + 255) / 256, 256, 0, stream>>>(Wo, Wob, DIM_ * DIM_ / 4);

    // gemm1: t = x @ Wt^T  (TM=64 -> 768 blocks = 3/CU)
    {
        dim3 grid(TOUT_ / 128, ROWS_ / 64);
        mfma_gemm_bt<64, TOUT_, DIM_><<<grid, 256, 0, stream>>>(Xb, Wtb, t);
    }

    // MFMA rotation + q/k bf16 pack (1 wave per position, no LDS)
    rot_qk_mfma<<<ROWS_ / 4, 256, 0, stream>>>(t, rot, wmask, Qb, Kb);

    // masked V^T + mask-row prep
    {
        dim3 grid(32, 16);
        prep_vt<<<grid, 256, 0, stream>>>(t, wmask, VtG);
    }

    // MFMA flash taylor-attention v4 (32x32 MFMA, 4-slot split-K)
    {
        dim3 grid(32, 8, 4);
        tmha_attn_mfma<<<grid, 256, 0, stream>>>(Qb, Kb, VtG, numer, den);
    }
    attn_combine<<<(ROWS_ * 128) / 256, 256, 0, stream>>>(numer, den, attnAb);

    // gemm2: out = attn @ Wo^T  (TM=64 -> 256 blocks = 1/CU)
    {
        dim3 grid(DIM_ / 128, ROWS_ / 64);
        mfma_gemm_bt<64, DIM_, DIM_><<<grid, 256, 0, stream>>>(attnAb, Wob, (float*)d_out);
    }
}